// Round 1
// baseline (3076.857 us; speedup 1.0000x reference)
//
#include <hip/hip_runtime.h>

#define B_ 16
#define C_ 512
#define N_ 2048
#define D_ 64

// ---------------- Kernel 1: Q/K projection ----------------
// Q[b][n][o] = sum_c Wq[o][c] * x[b][c][n] + bq[o]   (K likewise)
__global__ __launch_bounds__(256) void qk_proj(
    const float* __restrict__ x,
    const float* __restrict__ Wq, const float* __restrict__ bq,
    const float* __restrict__ Wk, const float* __restrict__ bk,
    float* __restrict__ Q, float* __restrict__ K) {
  __shared__ float xs[16][64];
  __shared__ float wqs[64][17];
  __shared__ float wks[64][17];
  const int b = blockIdx.x;
  const int n0 = blockIdx.y * 64;
  const int t = threadIdx.x;
  const int o = t & 63, ig = t >> 6;
  float qacc[16], kacc[16];
#pragma unroll
  for (int i = 0; i < 16; i++) { qacc[i] = 0.f; kacc[i] = 0.f; }

  for (int c0 = 0; c0 < C_; c0 += 16) {
    // x tile: 16 c-rows x 64 n, vectorized
    {
      const int kk = t >> 4, n4 = t & 15;
      *(float4*)&xs[kk][n4 * 4] =
          *(const float4*)&x[((size_t)b * C_ + c0 + kk) * N_ + n0 + n4 * 4];
    }
    // weight tiles: 64 o x 16 c (scalar loads; +1 pad -> conflict-free reads)
#pragma unroll
    for (int r = 0; r < 4; r++) {
      int idx = r * 256 + t;
      int oo = idx >> 4, c2 = idx & 15;
      wqs[oo][c2] = Wq[(size_t)oo * C_ + c0 + c2];
      wks[oo][c2] = Wk[(size_t)oo * C_ + c0 + c2];
    }
    __syncthreads();
#pragma unroll
    for (int cc = 0; cc < 16; cc++) {
      float wq = wqs[o][cc], wk = wks[o][cc];
#pragma unroll
      for (int ii = 0; ii < 16; ii++) {
        float xv = xs[cc][ig * 16 + ii];   // wave-uniform -> broadcast
        qacc[ii] += xv * wq;
        kacc[ii] += xv * wk;
      }
    }
    __syncthreads();
  }
  const float bqv = bq[o], bkv = bk[o];
#pragma unroll
  for (int ii = 0; ii < 16; ii++) {
    int n = n0 + ig * 16 + ii;
    Q[((size_t)b * N_ + n) * D_ + o] = qacc[ii] + bqv;  // coalesced over o
    K[((size_t)b * N_ + n) * D_ + o] = kacc[ii] + bkv;
  }
}

// ---------------- Kernel 2: V projection (transposed output) ----------------
// Vt[b][n][c] = sum_k Wv[c][k] * x[b][k][n] + bv[c]
__global__ __launch_bounds__(256) void v_proj(
    const float* __restrict__ x,
    const float* __restrict__ Wv, const float* __restrict__ bv,
    float* __restrict__ Vt) {
  __shared__ float xs[16][64];
  __shared__ float wvs[64][17];
  const int b = blockIdx.x;
  const int c0 = blockIdx.y * 64;
  const int n0 = blockIdx.z * 64;
  const int t = threadIdx.x;
  const int cc = t & 63, ng = t >> 6;
  float acc[16];
#pragma unroll
  for (int i = 0; i < 16; i++) acc[i] = 0.f;

  for (int k0 = 0; k0 < C_; k0 += 16) {
    {
      const int kk = t >> 4, n4 = t & 15;
      *(float4*)&xs[kk][n4 * 4] =
          *(const float4*)&x[((size_t)b * C_ + k0 + kk) * N_ + n0 + n4 * 4];
    }
#pragma unroll
    for (int r = 0; r < 4; r++) {
      int idx = r * 256 + t;
      int co = idx >> 4, k2 = idx & 15;
      wvs[co][k2] = Wv[(size_t)(c0 + co) * C_ + k0 + k2];
    }
    __syncthreads();
#pragma unroll
    for (int k = 0; k < 16; k++) {
      float wv = wvs[cc][k];   // lane-varied, pad-17 conflict-free
#pragma unroll
      for (int ni = 0; ni < 16; ni += 4) {
        float4 xv = *(const float4*)&xs[k][ng * 16 + ni];  // uniform b128
        acc[ni + 0] += wv * xv.x;
        acc[ni + 1] += wv * xv.y;
        acc[ni + 2] += wv * xv.z;
        acc[ni + 3] += wv * xv.w;
      }
    }
    __syncthreads();
  }
  const float bvv = bv[c0 + cc];
#pragma unroll
  for (int ni = 0; ni < 16; ni++) {
    int n = n0 + ng * 16 + ni;
    Vt[((size_t)b * N_ + n) * C_ + c0 + cc] = acc[ni] + bvv;  // coalesced over cc
  }
}

// ---------------- Kernel 3: softmax row stats (online) ----------------
__global__ __launch_bounds__(256) void stats_k(
    const float* __restrict__ Q, const float* __restrict__ K,
    float* __restrict__ Ms, float* __restrict__ Ls) {
  __shared__ float ks[64][68];
  __shared__ float pm[4][64];
  __shared__ float pl[4][64];
  const int b = blockIdx.x;
  const int i0 = blockIdx.y * 64;
  const int t = threadIdx.x;
  const int i = t & 63, g = t >> 6;

  float4 qreg[16];
  const float4* qrow = (const float4*)&Q[((size_t)b * N_ + i0 + i) * D_];
#pragma unroll
  for (int r = 0; r < 16; r++) qreg[r] = qrow[r];

  float m = -1e30f, l = 0.f;
  for (int j0 = 0; j0 < N_; j0 += 64) {
#pragma unroll
    for (int r = 0; r < 4; r++) {
      int idx = r * 256 + t;          // float4 index
      int jj = idx >> 4, o4 = idx & 15;
      *(float4*)&ks[jj][o4 * 4] =
          *(const float4*)&K[((size_t)b * N_ + j0 + jj) * D_ + o4 * 4];
    }
    __syncthreads();
#pragma unroll
    for (int jj = 0; jj < 16; jj++) {
      int j = g * 16 + jj;
      float e = 0.f;
#pragma unroll
      for (int o4 = 0; o4 < 16; o4++) {
        float4 kv = *(const float4*)&ks[j][o4 * 4];  // uniform b128
        e += qreg[o4].x * kv.x + qreg[o4].y * kv.y +
             qreg[o4].z * kv.z + qreg[o4].w * kv.w;
      }
      float mn = fmaxf(m, e);
      l = l * __expf(m - mn) + __expf(e - mn);
      m = mn;
    }
    __syncthreads();
  }
  pm[g][i] = m; pl[g][i] = l;
  __syncthreads();
  if (t < 64) {
    float M = pm[0][t];
#pragma unroll
    for (int g2 = 1; g2 < 4; g2++) M = fmaxf(M, pm[g2][t]);
    float L = 0.f;
#pragma unroll
    for (int g2 = 0; g2 < 4; g2++) L += pl[g2][t] * __expf(pm[g2][t] - M);
    Ms[(size_t)b * N_ + i0 + t] = M;
    Ls[(size_t)b * N_ + i0 + t] = L;
  }
}

// ---------------- Kernel 4: fused P·V + gamma*out + x ----------------
// block: (b, 64 i's, 256 c's); recompute e-tile, p=exp(e-m) via LDS, PV accumulate
__global__ __launch_bounds__(256) void attn_out(
    const float* __restrict__ x,
    const float* __restrict__ Q, const float* __restrict__ K,
    const float* __restrict__ Vt,
    const float* __restrict__ Ms, const float* __restrict__ Ls,
    const float* __restrict__ gamma, float* __restrict__ out) {
  __shared__ float ks[64][68];
  __shared__ float ps[64][65];
  __shared__ float vs[16][256];
  const int b = blockIdx.x;
  const int i0 = blockIdx.y * 64;
  const int c0 = blockIdx.z * 256;
  const int t = threadIdx.x;
  const int i = t & 63, g = t >> 6;

  float4 qreg[16];
  const float4* qrow = (const float4*)&Q[((size_t)b * N_ + i0 + i) * D_];
#pragma unroll
  for (int r = 0; r < 16; r++) qreg[r] = qrow[r];
  const float m = Ms[(size_t)b * N_ + i0 + i];
  const float invl = 1.0f / Ls[(size_t)b * N_ + i0 + i];

  float4 acc[16];
#pragma unroll
  for (int r = 0; r < 16; r++) acc[r] = make_float4(0.f, 0.f, 0.f, 0.f);

  for (int j0 = 0; j0 < N_; j0 += 64) {
    // K tile
#pragma unroll
    for (int r = 0; r < 4; r++) {
      int idx = r * 256 + t;
      int jj = idx >> 4, o4 = idx & 15;
      *(float4*)&ks[jj][o4 * 4] =
          *(const float4*)&K[((size_t)b * N_ + j0 + jj) * D_ + o4 * 4];
    }
    __syncthreads();
    // e-tile + exp -> ps ; wave g produces j in [g*16, g*16+16)
#pragma unroll
    for (int jj = 0; jj < 16; jj++) {
      int j = g * 16 + jj;
      float e = 0.f;
#pragma unroll
      for (int o4 = 0; o4 < 16; o4++) {
        float4 kv = *(const float4*)&ks[j][o4 * 4];
        e += qreg[o4].x * kv.x + qreg[o4].y * kv.y +
             qreg[o4].z * kv.z + qreg[o4].w * kv.w;
      }
      ps[i][j] = __expf(e - m);
    }
    __syncthreads();
    // PV in 4 quarters of 16 j-rows (keeps LDS <= 64KB)
    for (int q4 = 0; q4 < 4; q4++) {
#pragma unroll
      for (int r2 = 0; r2 < 4; r2++) {
        int r = r2 * 4 + g;
        *(float4*)&vs[r][i * 4] =
            *(const float4*)&Vt[((size_t)b * N_ + j0 + q4 * 16 + r) * C_ + c0 + i * 4];
      }
      __syncthreads();
#pragma unroll
      for (int jj = 0; jj < 16; jj++) {
        float pv = ps[i][q4 * 16 + jj];   // lane-varied i, conflict-free (pad 65)
#pragma unroll
        for (int cg = 0; cg < 16; cg++) {
          float4 vv = *(const float4*)&vs[jj][g * 64 + cg * 4];  // uniform b128
          acc[cg].x += pv * vv.x;
          acc[cg].y += pv * vv.y;
          acc[cg].z += pv * vv.z;
          acc[cg].w += pv * vv.w;
        }
      }
      __syncthreads();
    }
  }
  const float gam = gamma[0];
#pragma unroll
  for (int cg = 0; cg < 16; cg++) {
    int c = c0 + g * 64 + cg * 4;
    size_t base = ((size_t)b * C_ + c) * N_ + i0 + i;
    out[base]           = x[base]           + gam * acc[cg].x * invl;
    out[base + N_]      = x[base + N_]      + gam * acc[cg].y * invl;
    out[base + 2 * N_]  = x[base + 2 * N_]  + gam * acc[cg].z * invl;
    out[base + 3 * N_]  = x[base + 3 * N_]  + gam * acc[cg].w * invl;
  }
}

extern "C" void kernel_launch(void* const* d_in, const int* in_sizes, int n_in,
                              void* d_out, int out_size, void* d_ws, size_t ws_size,
                              hipStream_t stream) {
  const float* x     = (const float*)d_in[0];
  const float* Wq    = (const float*)d_in[1];
  const float* bq    = (const float*)d_in[2];
  const float* Wk    = (const float*)d_in[3];
  const float* bk    = (const float*)d_in[4];
  const float* Wv    = (const float*)d_in[5];
  const float* bv    = (const float*)d_in[6];
  const float* gamma = (const float*)d_in[7];
  float* out = (float*)d_out;

  float* Q  = (float*)d_ws;                       // B*N*D
  float* K  = Q  + (size_t)B_ * N_ * D_;          // B*N*D
  float* Vt = K  + (size_t)B_ * N_ * D_;          // B*N*C
  float* Ms = Vt + (size_t)B_ * N_ * C_;          // B*N
  float* Ls = Ms + (size_t)B_ * N_;               // B*N

  qk_proj<<<dim3(B_, N_ / 64), 256, 0, stream>>>(x, Wq, bq, Wk, bk, Q, K);
  v_proj<<<dim3(B_, C_ / 64, N_ / 64), 256, 0, stream>>>(x, Wv, bv, Vt);
  stats_k<<<dim3(B_, N_ / 64), 256, 0, stream>>>(Q, K, Ms, Ls);
  attn_out<<<dim3(B_, N_ / 64, C_ / 256), 256, 0, stream>>>(x, Q, K, Vt, Ms, Ls, gamma, out);
}

// Round 2
// 496.324 us; speedup vs baseline: 6.1993x; 6.1993x over previous
//
#include <hip/hip_runtime.h>

#define B_ 16
#define C_ 512
#define N_ 2048
#define D_ 64

typedef unsigned short u16;
typedef unsigned int   u32;
typedef __bf16 bfv8 __attribute__((ext_vector_type(8)));
typedef float  f4   __attribute__((ext_vector_type(4)));
typedef float  f16v __attribute__((ext_vector_type(16)));

__device__ __forceinline__ u16 f2bf(float f) {
  u32 u = __float_as_uint(f);
  u32 r = (u + 0x7FFFu + ((u >> 16) & 1u)) >> 16;   // RNE
  return (u16)r;
}
__device__ __forceinline__ u32 pack2(float a, float b) {
  return (u32)f2bf(a) | ((u32)f2bf(b) << 16);
}

// ---------------- W -> bf16 (same layout) ----------------
__global__ __launch_bounds__(256) void conv_w(const float* __restrict__ src,
                                              u16* __restrict__ dst, int n4) {
  int i = blockIdx.x * 256 + threadIdx.x;
  if (i < n4) {
    float4 v = ((const float4*)src)[i];
    uint2 o = make_uint2(pack2(v.x, v.y), pack2(v.z, v.w));
    ((uint2*)dst)[i] = o;
  }
}

// ---------------- x[b][c][n] f32 -> xT[b][n][c] bf16 ----------------
__global__ __launch_bounds__(256) void transpose_x(const float* __restrict__ x,
                                                   u16* __restrict__ xT) {
  __shared__ float ts[64][65];   // stride 65: (c+n)%32 banks, 2-way free
  const int b = blockIdx.x, c0 = blockIdx.y * 64, n0 = blockIdx.z * 64;
  const int t = threadIdx.x;
  {
    const int cl = t >> 4, nq = t & 15;
#pragma unroll
    for (int p = 0; p < 4; p++) {
      const float4 v = *(const float4*)&x[((size_t)(b * C_) + c0 + p * 16 + cl) * N_ + n0 + nq * 4];
      ts[p * 16 + cl][nq * 4 + 0] = v.x;
      ts[p * 16 + cl][nq * 4 + 1] = v.y;
      ts[p * 16 + cl][nq * 4 + 2] = v.z;
      ts[p * 16 + cl][nq * 4 + 3] = v.w;
    }
  }
  __syncthreads();
  {
    const int ch = t & 7, nl = t >> 3;   // 8 c-chunks x 32 n rows per pass
#pragma unroll
    for (int p = 0; p < 2; p++) {
      int n = p * 32 + nl;
      u32 d[4];
#pragma unroll
      for (int i = 0; i < 4; i++)
        d[i] = pack2(ts[ch * 8 + 2 * i][n], ts[ch * 8 + 2 * i + 1][n]);
      *(uint4*)&xT[((size_t)(b * N_) + n0 + n) * C_ + c0 + ch * 8] =
          make_uint4(d[0], d[1], d[2], d[3]);
    }
  }
}

// ---------------- Q/K projection via MFMA ----------------
// D[d][n] = Wq[d][:]·xT[n][:] ; A=W (m=d), B=xT (n'=n). Output Qb[b][n][d] bf16.
__global__ __launch_bounds__(256) void proj_qk(
    const u16* __restrict__ Wqb, const u16* __restrict__ Wkb,
    const float* __restrict__ bq, const float* __restrict__ bk,
    const u16* __restrict__ xT, u16* __restrict__ Qb, u16* __restrict__ Kb) {
  const int b = blockIdx.x, n0 = blockIdx.y * 64;
  const int t = threadIdx.x, w = t >> 6, lane = t & 63;
  const int l15 = lane & 15, quad = lane >> 4;
  f4 accQ[4], accK[4];
#pragma unroll
  for (int dt = 0; dt < 4; dt++) { accQ[dt] = (f4)(0.0f); accK[dt] = (f4)(0.0f); }
  const size_t xrow = ((size_t)(b * N_) + n0 + w * 16 + l15) * C_;
  for (int kc = 0; kc < 16; kc++) {
    bfv8 bx = *(const bfv8*)&xT[xrow + kc * 32 + quad * 8];
#pragma unroll
    for (int dt = 0; dt < 4; dt++) {
      bfv8 aq = *(const bfv8*)&Wqb[(size_t)(dt * 16 + l15) * C_ + kc * 32 + quad * 8];
      bfv8 ak = *(const bfv8*)&Wkb[(size_t)(dt * 16 + l15) * C_ + kc * 32 + quad * 8];
      accQ[dt] = __builtin_amdgcn_mfma_f32_16x16x32_bf16(aq, bx, accQ[dt], 0, 0, 0);
      accK[dt] = __builtin_amdgcn_mfma_f32_16x16x32_bf16(ak, bx, accK[dt], 0, 0, 0);
    }
  }
  // D: col = n = l15, rows d = quad*4 + reg (contiguous per reg group)
  const size_t orow = ((size_t)(b * N_) + n0 + w * 16 + l15) * D_;
#pragma unroll
  for (int dt = 0; dt < 4; dt++) {
    f4 bq4 = *(const f4*)&bq[dt * 16 + quad * 4];
    f4 bk4 = *(const f4*)&bk[dt * 16 + quad * 4];
    *(uint2*)&Qb[orow + dt * 16 + quad * 4] =
        make_uint2(pack2(accQ[dt][0] + bq4[0], accQ[dt][1] + bq4[1]),
                   pack2(accQ[dt][2] + bq4[2], accQ[dt][3] + bq4[3]));
    *(uint2*)&Kb[orow + dt * 16 + quad * 4] =
        make_uint2(pack2(accK[dt][0] + bk4[0], accK[dt][1] + bk4[1]),
                   pack2(accK[dt][2] + bk4[2], accK[dt][3] + bk4[3]));
  }
}

// ---------------- V projection via MFMA: Vb[b][c][n] bf16 ----------------
__global__ __launch_bounds__(256) void proj_v(
    const u16* __restrict__ Wvb, const float* __restrict__ bv,
    const u16* __restrict__ xT, u16* __restrict__ Vb) {
  const int b = blockIdx.x, c0 = blockIdx.y * 128, n0 = blockIdx.z * 64;
  const int t = threadIdx.x, w = t >> 6, lane = t & 63;
  const int l31 = lane & 31, h = lane >> 5;
  f16v acc[2];
#pragma unroll
  for (int nt = 0; nt < 2; nt++) acc[nt] = (f16v)(0.0f);
  const int crow = c0 + w * 32 + l31;
  for (int kc = 0; kc < 32; kc++) {
    bfv8 a = *(const bfv8*)&Wvb[(size_t)crow * C_ + kc * 16 + h * 8];
#pragma unroll
    for (int nt = 0; nt < 2; nt++) {
      bfv8 bx = *(const bfv8*)&xT[((size_t)(b * N_) + n0 + nt * 32 + l31) * C_ + kc * 16 + h * 8];
      acc[nt] = __builtin_amdgcn_mfma_f32_32x32x16_bf16(a, bx, acc[nt], 0, 0, 0);
    }
  }
  // D: col = n = l31, row c = (reg&3) + 8*(reg>>2) + 4*h
#pragma unroll
  for (int nt = 0; nt < 2; nt++) {
#pragma unroll
    for (int g = 0; g < 4; g++) {
      f4 bv4 = *(const f4*)&bv[c0 + w * 32 + g * 8 + h * 4];
#pragma unroll
      for (int r = 0; r < 4; r++) {
        int cr = c0 + w * 32 + g * 8 + h * 4 + r;
        Vb[((size_t)(b * C_) + cr) * N_ + n0 + nt * 32 + l31] =
            f2bf(acc[nt][g * 4 + r] + bv4[r]);
      }
    }
  }
}

// ---------------- Fused attention: E^T -> exp -> PV -> gamma*o/l + x ----------------
__global__ __launch_bounds__(256, 4) void attn(
    const float* __restrict__ x, const u16* __restrict__ Qb,
    const u16* __restrict__ Kb, const u16* __restrict__ Vb,
    const float* __restrict__ gamma, float* __restrict__ out) {
  const int b = blockIdx.x, i0 = blockIdx.y * 64, cblk = blockIdx.z * 256;
  const int t = threadIdx.x, w = t >> 6, lane = t & 63;
  const int l15 = lane & 15, quad = lane >> 4;
  const int l31 = lane & 31, h = lane >> 5;
  __shared__ u16 Ps[64][72];     // P tile [i][j] bf16, stride 72
  __shared__ float invl[64];

  // Q B-frags for wave's i-subtile (it = w): B[n=i][k=d]
  bfv8 qf[2];
#pragma unroll
  for (int kc = 0; kc < 2; kc++)
    qf[kc] = *(const bfv8*)&Qb[((size_t)(b * N_) + i0 + w * 16 + l15) * D_ + kc * 32 + quad * 8];

  f16v acc[2][2];
#pragma unroll
  for (int mt = 0; mt < 2; mt++)
#pragma unroll
    for (int nt = 0; nt < 2; nt++) acc[mt][nt] = (f16v)(0.0f);
  float l_acc = 0.0f;

  for (int j0 = 0; j0 < N_; j0 += 64) {
    // E^T[j][i] for (jt, it=w): A = K (m=j), B = Q (n=i)
#pragma unroll
    for (int jt = 0; jt < 4; jt++) {
      f4 e = (f4)(0.0f);
#pragma unroll
      for (int kc = 0; kc < 2; kc++) {
        bfv8 kf = *(const bfv8*)&Kb[((size_t)(b * N_) + j0 + jt * 16 + l15) * D_ + kc * 32 + quad * 8];
        e = __builtin_amdgcn_mfma_f32_16x16x32_bf16(kf, qf[kc], e, 0, 0, 0);
      }
      // rows j = jt*16 + quad*4 + reg (contiguous), col i = w*16 + l15
      float p0 = __expf(e[0]), p1 = __expf(e[1]);
      float p2 = __expf(e[2]), p3 = __expf(e[3]);
      l_acc += (p0 + p1) + (p2 + p3);
      *(uint2*)&Ps[w * 16 + l15][jt * 16 + quad * 4] =
          make_uint2(pack2(p0, p1), pack2(p2, p3));
    }
    __syncthreads();
    // PV: A = P[m=i][k=j] from LDS, B = V[n=c][k=j] direct from global
#pragma unroll
    for (int kc = 0; kc < 4; kc++) {
      bfv8 pa[2], vb[2];
#pragma unroll
      for (int mt = 0; mt < 2; mt++)
        pa[mt] = *(const bfv8*)&Ps[mt * 32 + l31][kc * 16 + h * 8];
#pragma unroll
      for (int nt = 0; nt < 2; nt++)
        vb[nt] = *(const bfv8*)&Vb[((size_t)(b * C_) + cblk + w * 64 + nt * 32 + l31) * N_ + j0 + kc * 16 + h * 8];
#pragma unroll
      for (int mt = 0; mt < 2; mt++)
#pragma unroll
        for (int nt = 0; nt < 2; nt++)
          acc[mt][nt] = __builtin_amdgcn_mfma_f32_32x32x16_bf16(pa[mt], vb[nt], acc[mt][nt], 0, 0, 0);
    }
    __syncthreads();
  }

  // l: lane covers all jt and all quads' rows for i = w*16 + l15 -> reduce quads
  float lt = l_acc;
  lt += __shfl_xor(lt, 16, 64);
  lt += __shfl_xor(lt, 32, 64);
  if (lane < 16) invl[w * 16 + l15] = 1.0f / lt;
  __syncthreads();

  const float gam = gamma[0];
#pragma unroll
  for (int mt = 0; mt < 2; mt++) {
#pragma unroll
    for (int nt = 0; nt < 2; nt++) {
      int c = cblk + w * 64 + nt * 32 + l31;
#pragma unroll
      for (int g = 0; g < 4; g++) {
        int ib = mt * 32 + g * 8 + h * 4;       // rows i = ib + r
        f4 il = *(const f4*)&invl[ib];
        size_t off = ((size_t)(b * C_) + c) * N_ + i0 + ib;
        f4 xv = *(const f4*)&x[off];
        f4 o;
#pragma unroll
        for (int r = 0; r < 4; r++)
          o[r] = xv[r] + gam * acc[mt][nt][g * 4 + r] * il[r];
        *(f4*)&out[off] = o;
      }
    }
  }
}

extern "C" void kernel_launch(void* const* d_in, const int* in_sizes, int n_in,
                              void* d_out, int out_size, void* d_ws, size_t ws_size,
                              hipStream_t stream) {
  const float* x     = (const float*)d_in[0];
  const float* Wq    = (const float*)d_in[1];
  const float* bq    = (const float*)d_in[2];
  const float* Wk    = (const float*)d_in[3];
  const float* bk    = (const float*)d_in[4];
  const float* Wv    = (const float*)d_in[5];
  const float* bv    = (const float*)d_in[6];
  const float* gamma = (const float*)d_in[7];
  float* out = (float*)d_out;

  u16* wsu = (u16*)d_ws;
  u16* xT  = wsu;                                   // B*N*C
  u16* Qb  = xT  + (size_t)B_ * N_ * C_;            // B*N*D
  u16* Kb  = Qb  + (size_t)B_ * N_ * D_;            // B*N*D
  u16* Vb  = Kb  + (size_t)B_ * N_ * D_;            // B*C*N
  u16* Wqb = Vb  + (size_t)B_ * C_ * N_;            // D*C
  u16* Wkb = Wqb + (size_t)D_ * C_;                 // D*C
  u16* Wvb = Wkb + (size_t)D_ * C_;                 // C*C

  conv_w<<<dim3((D_ * C_ / 4 + 255) / 256), 256, 0, stream>>>(Wq, Wqb, D_ * C_ / 4);
  conv_w<<<dim3((D_ * C_ / 4 + 255) / 256), 256, 0, stream>>>(Wk, Wkb, D_ * C_ / 4);
  conv_w<<<dim3((C_ * C_ / 4 + 255) / 256), 256, 0, stream>>>(Wv, Wvb, C_ * C_ / 4);
  transpose_x<<<dim3(B_, C_ / 64, N_ / 64), 256, 0, stream>>>(x, xT);
  proj_qk<<<dim3(B_, N_ / 64), 256, 0, stream>>>(Wqb, Wkb, bq, bk, xT, Qb, Kb);
  proj_v<<<dim3(B_, C_ / 128, N_ / 64), 256, 0, stream>>>(Wvb, bv, xT, Vb);
  attn<<<dim3(B_, N_ / 64, C_ / 256), 256, 0, stream>>>(x, Qb, Kb, Vb, gamma, out);
}

// Round 3
// 374.248 us; speedup vs baseline: 8.2214x; 1.3262x over previous
//
#include <hip/hip_runtime.h>

#define B_ 16
#define C_ 512
#define N_ 2048
#define D_ 64

typedef unsigned short u16;
typedef unsigned int   u32;
typedef __bf16 bfv4 __attribute__((ext_vector_type(4)));
typedef __bf16 bfv8 __attribute__((ext_vector_type(8)));
typedef float  f4   __attribute__((ext_vector_type(4)));
typedef float  f16v __attribute__((ext_vector_type(16)));

__device__ __forceinline__ u16 f2bf(float f) {
  u32 u = __float_as_uint(f);
  u32 r = (u + 0x7FFFu + ((u >> 16) & 1u)) >> 16;   // RNE
  return (u16)r;
}
__device__ __forceinline__ u32 pack2(float a, float b) {
  return (u32)f2bf(a) | ((u32)f2bf(b) << 16);
}
// 8-byte-aligned LDS load of 8 bf16 (2 x ds_read_b64)
__device__ __forceinline__ bfv8 ld8(const u16* p) {
  bfv4 lo = *(const bfv4*)p;
  bfv4 hi = *(const bfv4*)(p + 4);
  bfv8 r;
  r[0] = lo[0]; r[1] = lo[1]; r[2] = lo[2]; r[3] = lo[3];
  r[4] = hi[0]; r[5] = hi[1]; r[6] = hi[2]; r[7] = hi[3];
  return r;
}

// ---------------- all W -> bf16, one launch ----------------
__global__ __launch_bounds__(256) void conv_all(
    const float* __restrict__ Wq, const float* __restrict__ Wk,
    const float* __restrict__ Wv,
    u16* __restrict__ Wqb, u16* __restrict__ Wkb, u16* __restrict__ Wvb) {
  const int q4 = D_ * C_ / 4;   // 8192
  const int v4 = C_ * C_ / 4;   // 65536
  int i = blockIdx.x * 256 + threadIdx.x;
  const float* src; u16* dst; int j;
  if (i < q4)            { src = Wq; dst = Wqb; j = i; }
  else if (i < 2 * q4)   { src = Wk; dst = Wkb; j = i - q4; }
  else                   { j = i - 2 * q4; if (j >= v4) return; src = Wv; dst = Wvb; }
  float4 v = ((const float4*)src)[j];
  ((uint2*)dst)[j] = make_uint2(pack2(v.x, v.y), pack2(v.z, v.w));
}

// ---------------- fused transpose + Q/K/V projection ----------------
// Block (b, n0): stage x[b][:][n0..n0+63] transposed to LDS bf16, then
// QK proj (16x16x32) and V proj (32x32x16) straight out of LDS.
#define XS_STR 516   // u16 row stride: 258 dwords -> 2-way bank pattern (free)
__global__ __launch_bounds__(256, 2) void proj_all(
    const float* __restrict__ x,
    const u16* __restrict__ Wqb, const u16* __restrict__ Wkb,
    const float* __restrict__ bq, const float* __restrict__ bk,
    const u16* __restrict__ Wvb, const float* __restrict__ bv,
    u16* __restrict__ Qb, u16* __restrict__ Kb, u16* __restrict__ Vb) {
  __shared__ u16 xs[64][XS_STR];    // [n][c]
  const int b = blockIdx.x, n0 = blockIdx.y * 64;
  const int t = threadIdx.x;
  const int w = t >> 6, lane = t & 63;
  const int l15 = lane & 15, quad = lane >> 4;
  const int l31 = lane & 31, h = lane >> 5;

  // ---- stage + transpose: 16 passes x (16 n-float4 x 16 c-pairs) ----
  {
    const int n4 = t & 15, cp = t >> 4;
    for (int p = 0; p < 16; p++) {
      int c = p * 32 + cp * 2;
      const size_t rb = ((size_t)(b * C_) + c) * N_ + n0 + n4 * 4;
      float4 a = *(const float4*)&x[rb];
      float4 bb = *(const float4*)&x[rb + N_];
      *(u32*)&xs[n4 * 4 + 0][c] = pack2(a.x, bb.x);
      *(u32*)&xs[n4 * 4 + 1][c] = pack2(a.y, bb.y);
      *(u32*)&xs[n4 * 4 + 2][c] = pack2(a.z, bb.z);
      *(u32*)&xs[n4 * 4 + 3][c] = pack2(a.w, bb.w);
    }
  }
  __syncthreads();

  // ---- Q/K: wave w owns n-subtile w*16 ----
  {
    f4 accQ[4], accK[4];
#pragma unroll
    for (int mt = 0; mt < 4; mt++) { accQ[mt] = (f4)(0.0f); accK[mt] = (f4)(0.0f); }
    const u16* xrow = &xs[w * 16 + l15][0];
    for (int kc = 0; kc < 16; kc++) {
      bfv8 bx = ld8(&xrow[kc * 32 + quad * 8]);
#pragma unroll
      for (int mt = 0; mt < 4; mt++) {
        bfv8 aq = *(const bfv8*)&Wqb[(size_t)(mt * 16 + l15) * C_ + kc * 32 + quad * 8];
        bfv8 ak = *(const bfv8*)&Wkb[(size_t)(mt * 16 + l15) * C_ + kc * 32 + quad * 8];
        accQ[mt] = __builtin_amdgcn_mfma_f32_16x16x32_bf16(aq, bx, accQ[mt], 0, 0, 0);
        accK[mt] = __builtin_amdgcn_mfma_f32_16x16x32_bf16(ak, bx, accK[mt], 0, 0, 0);
      }
    }
    const size_t orow = ((size_t)(b * N_) + n0 + w * 16 + l15) * D_;
#pragma unroll
    for (int mt = 0; mt < 4; mt++) {
      f4 bq4 = *(const f4*)&bq[mt * 16 + quad * 4];
      f4 bk4 = *(const f4*)&bk[mt * 16 + quad * 4];
      *(uint2*)&Qb[orow + mt * 16 + quad * 4] =
          make_uint2(pack2(accQ[mt][0] + bq4[0], accQ[mt][1] + bq4[1]),
                     pack2(accQ[mt][2] + bq4[2], accQ[mt][3] + bq4[3]));
      *(uint2*)&Kb[orow + mt * 16 + quad * 4] =
          make_uint2(pack2(accK[mt][0] + bk4[0], accK[mt][1] + bk4[1]),
                     pack2(accK[mt][2] + bk4[2], accK[mt][3] + bk4[3]));
    }
  }

  // ---- V: wave w owns c-range w*128, 4 mt x 2 nt of 32x32x16 ----
  {
    f16v acc[4][2];
#pragma unroll
    for (int mt = 0; mt < 4; mt++)
#pragma unroll
      for (int nt = 0; nt < 2; nt++) acc[mt][nt] = (f16v)(0.0f);
    for (int kc = 0; kc < 32; kc++) {
      bfv8 bx[2];
#pragma unroll
      for (int nt = 0; nt < 2; nt++)
        bx[nt] = ld8(&xs[nt * 32 + l31][kc * 16 + h * 8]);
#pragma unroll
      for (int mt = 0; mt < 4; mt++) {
        bfv8 a = *(const bfv8*)&Wvb[(size_t)(w * 128 + mt * 32 + l31) * C_ + kc * 16 + h * 8];
#pragma unroll
        for (int nt = 0; nt < 2; nt++)
          acc[mt][nt] = __builtin_amdgcn_mfma_f32_32x32x16_bf16(a, bx[nt], acc[mt][nt], 0, 0, 0);
      }
    }
#pragma unroll
    for (int mt = 0; mt < 4; mt++)
#pragma unroll
      for (int nt = 0; nt < 2; nt++)
#pragma unroll
        for (int g = 0; g < 4; g++) {
          f4 bv4 = *(const f4*)&bv[w * 128 + mt * 32 + g * 8 + h * 4];
#pragma unroll
          for (int r = 0; r < 4; r++) {
            int c = w * 128 + mt * 32 + g * 8 + h * 4 + r;
            Vb[((size_t)(b * C_) + c) * N_ + n0 + nt * 32 + l31] =
                f2bf(acc[mt][nt][g * 4 + r] + bv4[r]);
          }
        }
  }
}

// ---------------- fused attention, full-C blocks ----------------
// Grid (B, N/64) = 512 blocks (2/CU). Ps double-buffered -> 1 barrier/iter.
#define PS_STR 68   // u16: 34 dwords -> 2-way bank pattern (free)
__global__ __launch_bounds__(256, 2) void attn(
    const float* __restrict__ x, const u16* __restrict__ Qb,
    const u16* __restrict__ Kb, const u16* __restrict__ Vb,
    const float* __restrict__ gamma, float* __restrict__ out) {
  __shared__ u16 Ps[2][64][PS_STR];
  __shared__ float invl[64];
  const int b = blockIdx.x, i0 = blockIdx.y * 64;
  const int t = threadIdx.x, w = t >> 6, lane = t & 63;
  const int l15 = lane & 15, quad = lane >> 4;
  const int l31 = lane & 31, h = lane >> 5;

  bfv8 qf[2];
#pragma unroll
  for (int kc = 0; kc < 2; kc++)
    qf[kc] = *(const bfv8*)&Qb[((size_t)(b * N_) + i0 + w * 16 + l15) * D_ + kc * 32 + quad * 8];

  f16v acc[2][4];   // mt: i 0..63, nt: c = w*128 + nt*32
#pragma unroll
  for (int mt = 0; mt < 2; mt++)
#pragma unroll
    for (int nt = 0; nt < 4; nt++) acc[mt][nt] = (f16v)(0.0f);
  float l_acc = 0.0f;

  const u16* Vbase = &Vb[((size_t)(b * C_) + w * 128) * N_];

  int buf = 0;
  for (int j0 = 0; j0 < N_; j0 += 64, buf ^= 1) {
    // E^T: wave w computes cols i = w*16..+15, all 64 j
#pragma unroll
    for (int jt = 0; jt < 4; jt++) {
      f4 e = (f4)(0.0f);
#pragma unroll
      for (int kc = 0; kc < 2; kc++) {
        bfv8 kf = *(const bfv8*)&Kb[((size_t)(b * N_) + j0 + jt * 16 + l15) * D_ + kc * 32 + quad * 8];
        e = __builtin_amdgcn_mfma_f32_16x16x32_bf16(kf, qf[kc], e, 0, 0, 0);
      }
      float p0 = __expf(e[0]), p1 = __expf(e[1]);
      float p2 = __expf(e[2]), p3 = __expf(e[3]);
      l_acc += (p0 + p1) + (p2 + p3);
      *(uint2*)&Ps[buf][w * 16 + l15][jt * 16 + quad * 4] =
          make_uint2(pack2(p0, p1), pack2(p2, p3));
    }
    // prefetch V for kc=0 before the barrier (independent of Ps)
    bfv8 vb0[4];
#pragma unroll
    for (int nt = 0; nt < 4; nt++)
      vb0[nt] = *(const bfv8*)&Vbase[(size_t)(nt * 32 + l31) * N_ + j0 + h * 8];
    __syncthreads();
    // PV: A = P (LDS), B = V (global)
#pragma unroll
    for (int kc = 0; kc < 4; kc++) {
      bfv8 pa[2];
#pragma unroll
      for (int mt = 0; mt < 2; mt++)
        pa[mt] = ld8(&Ps[buf][mt * 32 + l31][kc * 16 + h * 8]);
      bfv8 vb[4];
      if (kc == 0) {
#pragma unroll
        for (int nt = 0; nt < 4; nt++) vb[nt] = vb0[nt];
      } else {
#pragma unroll
        for (int nt = 0; nt < 4; nt++)
          vb[nt] = *(const bfv8*)&Vbase[(size_t)(nt * 32 + l31) * N_ + j0 + kc * 16 + h * 8];
      }
#pragma unroll
      for (int mt = 0; mt < 2; mt++)
#pragma unroll
        for (int nt = 0; nt < 4; nt++)
          acc[mt][nt] = __builtin_amdgcn_mfma_f32_32x32x16_bf16(pa[mt], vb[nt], acc[mt][nt], 0, 0, 0);
    }
  }

  float lt = l_acc;
  lt += __shfl_xor(lt, 16, 64);
  lt += __shfl_xor(lt, 32, 64);
  if (lane < 16) invl[w * 16 + l15] = 1.0f / lt;
  __syncthreads();

  const float gam = gamma[0];
#pragma unroll
  for (int mt = 0; mt < 2; mt++)
#pragma unroll
    for (int nt = 0; nt < 4; nt++) {
      int c = w * 128 + nt * 32 + l31;
#pragma unroll
      for (int g = 0; g < 4; g++) {
        int ib = mt * 32 + g * 8 + h * 4;
        f4 il = *(const f4*)&invl[ib];
        size_t off = ((size_t)(b * C_) + c) * N_ + i0 + ib;
        f4 xv = *(const f4*)&x[off];
        f4 o;
#pragma unroll
        for (int r = 0; r < 4; r++)
          o[r] = xv[r] + gam * acc[mt][nt][g * 4 + r] * il[r];
        *(f4*)&out[off] = o;
      }
    }
}

extern "C" void kernel_launch(void* const* d_in, const int* in_sizes, int n_in,
                              void* d_out, int out_size, void* d_ws, size_t ws_size,
                              hipStream_t stream) {
  const float* x     = (const float*)d_in[0];
  const float* Wq    = (const float*)d_in[1];
  const float* bq    = (const float*)d_in[2];
  const float* Wk    = (const float*)d_in[3];
  const float* bk    = (const float*)d_in[4];
  const float* Wv    = (const float*)d_in[5];
  const float* bv    = (const float*)d_in[6];
  const float* gamma = (const float*)d_in[7];
  float* out = (float*)d_out;

  u16* wsu = (u16*)d_ws;
  u16* Qb  = wsu;                                   // B*N*D
  u16* Kb  = Qb  + (size_t)B_ * N_ * D_;            // B*N*D
  u16* Vb  = Kb  + (size_t)B_ * N_ * D_;            // B*C*N
  u16* Wqb = Vb  + (size_t)B_ * C_ * N_;            // D*C
  u16* Wkb = Wqb + (size_t)D_ * C_;                 // D*C
  u16* Wvb = Wkb + (size_t)D_ * C_;                 // C*C

  conv_all<<<dim3(320), 256, 0, stream>>>(Wq, Wk, Wv, Wqb, Wkb, Wvb);
  proj_all<<<dim3(B_, N_ / 64), 256, 0, stream>>>(x, Wqb, Wkb, bq, bk, Wvb, bv, Qb, Kb, Vb);
  attn<<<dim3(B_, N_ / 64), 256, 0, stream>>>(x, Qb, Kb, Vb, gamma, out);
}